// Round 3
// baseline (357.057 us; speedup 1.0000x reference)
//
#include <hip/hip_runtime.h>

// Problem constants (fixed by the reference file)
#define BB 4096
#define FF 16384
#define GG 512
#define SS 32
#define HALF (FF / 2)   // 8192 floats = 32 KiB per row-half

typedef float v4f __attribute__((ext_vector_type(4)));

// v[idx[i]] = w[i] * fc[i>>5].
// group_idx is arange(G*S).reshape(G,S): a permutation covering 0..F-1
// exactly once (G*S == F). Plain scatter store, no memset, no atomics.
__global__ void build_v_kernel(const int* __restrict__ idx,
                               const float* __restrict__ w,
                               const float* __restrict__ fc,
                               float* __restrict__ v) {
    int i = blockIdx.x * blockDim.x + threadIdx.x;
    if (i < GG * SS) {
        v[idx[i]] = w[i] * fc[i >> 5];  // SS = 32
    }
}

// GEMV, A/B round: identical math to rounds 0-2 but
//  - NO nontemporal hint on x loads (the one constant across all three
//    prior variants -- testing whether `nt` throttles the read path),
//  - NO LDS / __syncthreads (loads issue from cycle 0; v reads are
//    L2-resident co-issued globals, proven cost-neutral in round 2),
//  - 2048 blocks x 4 waves = 8192 waves; each wave owns one (row, half):
//    32 KiB contiguous stream; 8 blocks/CU -> 32 waves/CU max occupancy,
//  - 4 independent v4f accumulators, 16 x-loads in flight per lane.
__global__ __launch_bounds__(256, 8) void gemv_kernel(const float* __restrict__ x,
                                                      const float* __restrict__ v,
                                                      float* __restrict__ part) {
    const int tid  = threadIdx.x;
    const int wave = tid >> 6;
    const int lane = tid & 63;
    const int h    = (blockIdx.x << 2) + wave;   // 0..8191
    const int row  = h >> 1;
    const int c    = h & 1;

    const v4f* __restrict__ x4 = (const v4f*)(x + (size_t)row * FF + c * HALF);
    const v4f* __restrict__ v4 = (const v4f*)(v + c * HALF);

    v4f a0 = {0.f, 0.f, 0.f, 0.f}, a1 = a0, a2 = a0, a3 = a0;
    // HALF/4 = 2048 v4f over 64 lanes, 4 per trip -> 8 trips; unroll 2
    // -> batches of 8 x + 8 v loads in flight per lane.
    #pragma unroll 2
    for (int i = lane; i < HALF / 4; i += 256) {
        v4f x0 = x4[i];
        v4f x1 = x4[i + 64];
        v4f x2 = x4[i + 128];
        v4f x3 = x4[i + 192];
        a0 += x0 * v4[i];
        a1 += x1 * v4[i + 64];
        a2 += x2 * v4[i + 128];
        a3 += x3 * v4[i + 192];
    }
    v4f acc = (a0 + a1) + (a2 + a3);
    float sum = (acc.x + acc.y) + (acc.z + acc.w);

    #pragma unroll
    for (int off = 32; off > 0; off >>= 1)
        sum += __shfl_down(sum, off, 64);

    if (lane == 0) part[c * BB + row] = sum;
}

// out[b] = part[0][b] + part[1][b]
__global__ void combine_kernel(const float* __restrict__ part,
                               float* __restrict__ out) {
    int i = blockIdx.x * blockDim.x + threadIdx.x;
    if (i < BB) out[i] = part[i] + part[BB + i];
}

extern "C" void kernel_launch(void* const* d_in, const int* in_sizes, int n_in,
                              void* d_out, int out_size, void* d_ws, size_t ws_size,
                              hipStream_t stream) {
    const float* x   = (const float*)d_in[0];   // (B, F) fp32
    const int*   idx = (const int*)d_in[1];     // (G, S) int
    const float* w   = (const float*)d_in[2];   // (G, S) fp32
    const float* fc  = (const float*)d_in[3];   // (G, 1) fp32
    float* out = (float*)d_out;                 // (B, 1) fp32
    float* v    = (float*)d_ws;                 // F fp32 scratch (64 KiB)
    float* part = v + FF;                       // 2*B fp32 partials (32 KiB)

    build_v_kernel<<<(GG * SS + 255) / 256, 256, 0, stream>>>(idx, w, fc, v);
    gemv_kernel<<<BB / 2, 256, 0, stream>>>(x, v, part);
    combine_kernel<<<(BB + 255) / 256, 256, 0, stream>>>(part, out);
}